// Round 1
// baseline (654.170 us; speedup 1.0000x reference)
//
#include <hip/hip_runtime.h>

typedef __bf16 bf16x8 __attribute__((ext_vector_type(8)));
typedef float floatx4 __attribute__((ext_vector_type(4)));
typedef unsigned short ushortx8 __attribute__((ext_vector_type(8)));

__device__ __forceinline__ unsigned short f2b(float f) {
    union { float f; unsigned u; } v; v.f = f;
    unsigned r = v.u + 0x7fffu + ((v.u >> 16) & 1u);   // RNE
    return (unsigned short)(r >> 16);
}

// ---------------- CSR build ----------------

__global__ void deg_count_kernel(const int* __restrict__ dst, int* __restrict__ deg, int nE) {
    int e = blockIdx.x * blockDim.x + threadIdx.x;
    if (e < nE) atomicAdd(&deg[dst[e]], 1);
}

__global__ void scan_kernel(const int* __restrict__ deg, int* __restrict__ off, int n) {
    __shared__ int tmp[1024];
    __shared__ int carry;
    int tid = threadIdx.x;
    if (tid == 0) carry = 0;
    __syncthreads();
    for (int base = 0; base < n; base += 1024) {
        int idx = base + tid;
        int v = (idx < n) ? deg[idx] : 0;
        tmp[tid] = v;
        __syncthreads();
        for (int o = 1; o < 1024; o <<= 1) {
            int t = (tid >= o) ? tmp[tid - o] : 0;
            __syncthreads();
            tmp[tid] += t;
            __syncthreads();
        }
        if (idx < n) off[idx] = carry + tmp[tid] - v;   // exclusive
        __syncthreads();
        if (tid == 0) carry += tmp[1023];
        __syncthreads();
    }
    if (tid == 0) off[n] = carry;
}

__global__ void fill_kernel(const int* __restrict__ src, const int* __restrict__ dst,
                            const int* __restrict__ off, int* __restrict__ cursor,
                            int* __restrict__ csr, int nE) {
    int e = blockIdx.x * blockDim.x + threadIdx.x;
    if (e < nE) {
        int d = dst[e];
        int pos = atomicAdd(&cursor[d], 1);
        csr[off[d] + pos] = src[e];
    }
}

// ---------------- aggregation: one wave per node, m -> bf16 A[:, 0:512] ----------------

__global__ void agg_kernel(const float* __restrict__ x, const int* __restrict__ off,
                           const int* __restrict__ csr, unsigned short* __restrict__ Abuf,
                           int n) {
    int wid = (int)((blockIdx.x * (long)blockDim.x + threadIdx.x) >> 6);
    int l = threadIdx.x & 63;
    if (wid >= n) return;
    int beg = off[wid], end = off[wid + 1];
    float4 a0 = make_float4(0.f, 0.f, 0.f, 0.f);
    float4 a1 = make_float4(0.f, 0.f, 0.f, 0.f);
    for (int e = beg; e < end; e++) {
        int s = csr[e];
        const float4* row = (const float4*)(x + (long)s * 512);
        float4 v0 = row[l * 2], v1 = row[l * 2 + 1];
        a0.x += v0.x; a0.y += v0.y; a0.z += v0.z; a0.w += v0.w;
        a1.x += v1.x; a1.y += v1.y; a1.z += v1.z; a1.w += v1.w;
    }
    int d = end - beg;
    float inv = 1.0f / (float)(d > 0 ? d : 1);
    ushortx8 o8;
    o8[0] = f2b(a0.x * inv); o8[1] = f2b(a0.y * inv);
    o8[2] = f2b(a0.z * inv); o8[3] = f2b(a0.w * inv);
    o8[4] = f2b(a1.x * inv); o8[5] = f2b(a1.y * inv);
    o8[6] = f2b(a1.z * inv); o8[7] = f2b(a1.w * inv);
    *(ushortx8*)(Abuf + (long)wid * 1024 + l * 8) = o8;
}

// ---------------- x -> bf16 A[:, 512:1024]; zero pad rows ----------------

__global__ void convx_kernel(const float* __restrict__ x, unsigned short* __restrict__ Abuf,
                             int Mreal, int Mpad) {
    long t = (long)blockIdx.x * blockDim.x + threadIdx.x;
    long row = t >> 7;
    int c8 = (int)(t & 127) * 8;
    if (row >= Mpad) return;
    unsigned short* dp = Abuf + row * 1024 + c8;
    if (row < Mreal) {
        if (c8 >= 512) {
            const float4* p4 = (const float4*)(x + row * 512 + (c8 - 512));
            float4 v0 = p4[0], v1 = p4[1];
            ushortx8 o8;
            o8[0] = f2b(v0.x); o8[1] = f2b(v0.y); o8[2] = f2b(v0.z); o8[3] = f2b(v0.w);
            o8[4] = f2b(v1.x); o8[5] = f2b(v1.y); o8[6] = f2b(v1.z); o8[7] = f2b(v1.w);
            *(ushortx8*)dp = o8;
        }
    } else {
        ushortx8 z = {0, 0, 0, 0, 0, 0, 0, 0};
        *(ushortx8*)dp = z;
    }
}

// ---------------- Wcat[o][k] = k<512 ? W_l[o][k] : W_r[o][k-512], bf16 ----------------

__global__ void convw_kernel(const float* __restrict__ Wl, const float* __restrict__ Wr,
                             unsigned short* __restrict__ Wcat) {
    int t = blockIdx.x * blockDim.x + threadIdx.x;   // 512 * 128
    int o = t >> 7;
    int c8 = (t & 127) * 8;
    const float* p = (c8 < 512) ? (Wl + o * 512 + c8) : (Wr + o * 512 + (c8 - 512));
    float4 v0 = ((const float4*)p)[0], v1 = ((const float4*)p)[1];
    ushortx8 o8;
    o8[0] = f2b(v0.x); o8[1] = f2b(v0.y); o8[2] = f2b(v0.z); o8[3] = f2b(v0.w);
    o8[4] = f2b(v1.x); o8[5] = f2b(v1.y); o8[6] = f2b(v1.z); o8[7] = f2b(v1.w);
    *(ushortx8*)(Wcat + (long)o * 1024 + c8) = o8;
}

// ---------------- GEMM: out = A(Mx1024,bf16) . Wcat(512x1024,bf16)^T + bias ----------------
// m97 structure: 128x128 tile, BK=32, 4 waves 2x2 each 64x64 (4x4 MFMA 16x16x32)

__global__ __launch_bounds__(256, 2)
void gemm_kernel(const unsigned short* __restrict__ A, const unsigned short* __restrict__ B,
                 const float* __restrict__ bl, const int* __restrict__ deg,
                 float* __restrict__ out, int Mreal) {
    __shared__ unsigned short As[128 * 32];   // 8 KB, row stride 32 (unpadded: global_load_lds layout)
    __shared__ unsigned short Bs[128 * 32];
    int tid = threadIdx.x;
    int w = tid >> 6, l = tid & 63;
    long i0 = (long)blockIdx.y * 128;
    int n0 = blockIdx.x * 128;
    int wm = (w >> 1) * 64, wn = (w & 1) * 64;
    int r = l & 15, q = l >> 4;
    int srow = l >> 2;          // row within 16-row segment
    int sch = (l & 3) * 8;      // k-chunk (8 bf16 = 16B)

    floatx4 acc[4][4] = {};

    for (int k0 = 0; k0 < 1024; k0 += 32) {
#pragma unroll
        for (int j = 0; j < 2; j++) {
            int s = w * 2 + j;
            int row = s * 16 + srow;
            const unsigned short* ga = A + (i0 + row) * 1024 + k0 + sch;
            const unsigned short* gb = B + (long)(n0 + row) * 1024 + k0 + sch;
            __builtin_amdgcn_global_load_lds(
                (__attribute__((address_space(1))) void*)(uintptr_t)ga,
                (__attribute__((address_space(3))) void*)(uintptr_t)(As + s * 512), 16, 0, 0);
            __builtin_amdgcn_global_load_lds(
                (__attribute__((address_space(1))) void*)(uintptr_t)gb,
                (__attribute__((address_space(3))) void*)(uintptr_t)(Bs + s * 512), 16, 0, 0);
        }
        __syncthreads();
        bf16x8 af[4], bfr[4];
#pragma unroll
        for (int a = 0; a < 4; a++)
            af[a] = *(const bf16x8*)(As + (wm + a * 16 + r) * 32 + q * 8);
#pragma unroll
        for (int b = 0; b < 4; b++)
            bfr[b] = *(const bf16x8*)(Bs + (wn + b * 16 + r) * 32 + q * 8);
#pragma unroll
        for (int a = 0; a < 4; a++)
#pragma unroll
            for (int b = 0; b < 4; b++)
                acc[a][b] = __builtin_amdgcn_mfma_f32_16x16x32_bf16(af[a], bfr[b], acc[a][b], 0, 0, 0);
        __syncthreads();
    }

#pragma unroll
    for (int a = 0; a < 4; a++) {
        long rb = i0 + wm + a * 16 + q * 4;
#pragma unroll
        for (int rr = 0; rr < 4; rr++) {
            long row = rb + rr;
            if (row < Mreal) {
                bool hasdeg = deg[row] > 0;
#pragma unroll
                for (int b = 0; b < 4; b++) {
                    int col = n0 + wn + b * 16 + r;
                    float v = acc[a][b][rr];
                    if (hasdeg) v += bl[col];
                    out[row * 512 + col] = v;
                }
            }
        }
    }
}

// ---------------- launch ----------------

extern "C" void kernel_launch(void* const* d_in, const int* in_sizes, int n_in,
                              void* d_out, int out_size, void* d_ws, size_t ws_size,
                              hipStream_t stream) {
    const float* x  = (const float*)d_in[0];
    const int* eidx = (const int*)d_in[1];
    const float* Wl = (const float*)d_in[2];
    const float* bl = (const float*)d_in[3];
    const float* Wr = (const float*)d_in[4];
    float* out = (float*)d_out;

    int N  = in_sizes[0] / 512;
    int nE = in_sizes[1] / 2;
    const int* src = eidx;
    const int* dst = eidx + nE;
    int Mpad = (N + 127) & ~127;

    char* w = (char*)d_ws;
    size_t o = 0;
    auto alloc = [&](size_t bytes) { void* p = w + o; o = (o + bytes + 255) & ~255UL; return p; };
    int* deg    = (int*)alloc((size_t)N * 4);
    int* cursor = (int*)alloc((size_t)N * 4);
    int* off    = (int*)alloc((size_t)(N + 1) * 4);
    int* csr    = (int*)alloc((size_t)nE * 4);
    unsigned short* Wcat = (unsigned short*)alloc((size_t)512 * 1024 * 2);
    unsigned short* Abuf = (unsigned short*)alloc((size_t)Mpad * 1024 * 2);
    if (o > ws_size) return;   // workspace too small -> validation will flag

    hipMemsetAsync(deg, 0, (size_t)N * 4, stream);
    hipMemsetAsync(cursor, 0, (size_t)N * 4, stream);

    deg_count_kernel<<<(nE + 255) / 256, 256, 0, stream>>>(dst, deg, nE);
    scan_kernel<<<1, 1024, 0, stream>>>(deg, off, N);
    fill_kernel<<<(nE + 255) / 256, 256, 0, stream>>>(src, dst, off, cursor, csr, nE);
    agg_kernel<<<(N * 64 + 255) / 256, 256, 0, stream>>>(x, off, csr, Abuf, N);
    convx_kernel<<<(int)(((long)Mpad * 128 + 255) / 256), 256, 0, stream>>>(x, Abuf, N, Mpad);
    convw_kernel<<<(512 * 128) / 256, 256, 0, stream>>>(Wl, Wr, Wcat);

    dim3 g(512 / 128, Mpad / 128);   // col-block fastest: A-row reuse in L2/L3
    gemm_kernel<<<g, 256, 0, stream>>>(Abuf, Wcat, bl, deg, out, N);
}

// Round 2
// 484.886 us; speedup vs baseline: 1.3491x; 1.3491x over previous
//
#include <hip/hip_runtime.h>

typedef __bf16 bf16x8 __attribute__((ext_vector_type(8)));
typedef float floatx4 __attribute__((ext_vector_type(4)));
typedef unsigned short ushortx8 __attribute__((ext_vector_type(8)));

__device__ __forceinline__ unsigned short f2b(float f) {
    union { float f; unsigned u; } v; v.f = f;
    unsigned r = v.u + 0x7fffu + ((v.u >> 16) & 1u);   // RNE
    return (unsigned short)(r >> 16);
}

__device__ __forceinline__ float b2f(unsigned short b) {
    union { unsigned u; float f; } v; v.u = ((unsigned)b) << 16;
    return v.f;
}

// ---------------- CSR build ----------------

__global__ void deg_count_kernel(const int* __restrict__ dst, int* __restrict__ deg, int nE) {
    int e = blockIdx.x * blockDim.x + threadIdx.x;
    if (e < nE) atomicAdd(&deg[dst[e]], 1);
}

// hierarchical scan: 1024 elems per block
__global__ void scan1_kernel(const int* __restrict__ deg, int* __restrict__ bsum, int n) {
    __shared__ int s[256];
    int b = blockIdx.x, t = threadIdx.x;
    int base = b * 1024 + t * 4;
    int v = 0;
#pragma unroll
    for (int i = 0; i < 4; i++) { int idx = base + i; if (idx < n) v += deg[idx]; }
    s[t] = v; __syncthreads();
    for (int o = 128; o > 0; o >>= 1) { if (t < o) s[t] += s[t + o]; __syncthreads(); }
    if (t == 0) bsum[b] = s[0];
}

__global__ void scan2_kernel(int* __restrict__ bsum, int* __restrict__ off, int nb, int n) {
    // single tiny block: exclusive-scan nb (<=64) block sums, write grand total to off[n]
    if (threadIdx.x == 0) {
        int acc = 0;
        for (int i = 0; i < nb; i++) { int x = bsum[i]; bsum[i] = acc; acc += x; }
        off[n] = acc;
    }
}

__global__ void scan3_kernel(const int* __restrict__ deg, const int* __restrict__ bsum,
                             int* __restrict__ off, int n) {
    __shared__ int s[256];
    int b = blockIdx.x, t = threadIdx.x;
    int idx = b * 1024 + t * 4;
    int a0 = (idx     < n) ? deg[idx]     : 0;
    int a1 = (idx + 1 < n) ? deg[idx + 1] : 0;
    int a2 = (idx + 2 < n) ? deg[idx + 2] : 0;
    int a3 = (idx + 3 < n) ? deg[idx + 3] : 0;
    int tsum = a0 + a1 + a2 + a3;
    s[t] = tsum; __syncthreads();
    for (int o = 1; o < 256; o <<= 1) {
        int u = (t >= o) ? s[t - o] : 0;
        __syncthreads();
        s[t] += u;
        __syncthreads();
    }
    int excl = s[t] - tsum + bsum[b];
    if (idx     < n) off[idx]     = excl;
    if (idx + 1 < n) off[idx + 1] = excl + a0;
    if (idx + 2 < n) off[idx + 2] = excl + a0 + a1;
    if (idx + 3 < n) off[idx + 3] = excl + a0 + a1 + a2;
}

__global__ void fill_kernel(const int* __restrict__ src, const int* __restrict__ dst,
                            const int* __restrict__ off, int* __restrict__ cursor,
                            int* __restrict__ csr, int nE) {
    int e = blockIdx.x * blockDim.x + threadIdx.x;
    if (e < nE) {
        int d = dst[e];
        int pos = atomicAdd(&cursor[d], 1);
        csr[off[d] + pos] = src[e];
    }
}

// ---------------- x -> bf16 A[:, 512:1024]; zero pad rows ----------------
// must run BEFORE agg (agg gathers bf16 x from Abuf right half)

__global__ void convx_kernel(const float* __restrict__ x, unsigned short* __restrict__ Abuf,
                             int Mreal, int Mpad) {
    long t = (long)blockIdx.x * blockDim.x + threadIdx.x;
    long row = t >> 7;
    int c8 = (int)(t & 127) * 8;
    if (row >= Mpad) return;
    unsigned short* dp = Abuf + row * 1024 + c8;
    if (row < Mreal) {
        if (c8 >= 512) {
            const float4* p4 = (const float4*)(x + row * 512 + (c8 - 512));
            float4 v0 = p4[0], v1 = p4[1];
            ushortx8 o8;
            o8[0] = f2b(v0.x); o8[1] = f2b(v0.y); o8[2] = f2b(v0.z); o8[3] = f2b(v0.w);
            o8[4] = f2b(v1.x); o8[5] = f2b(v1.y); o8[6] = f2b(v1.z); o8[7] = f2b(v1.w);
            *(ushortx8*)dp = o8;
        }
    } else {
        ushortx8 z = {0, 0, 0, 0, 0, 0, 0, 0};
        *(ushortx8*)dp = z;
    }
}

// ---------------- aggregation: one wave per node, gathers bf16 x, m -> bf16 A[:, 0:512] ----

__global__ void agg_kernel(const unsigned short* __restrict__ Abuf_r,   // = Abuf (reads +512 half)
                           const int* __restrict__ off, const int* __restrict__ csr,
                           unsigned short* __restrict__ Abuf_w, int n) {
    int wid = (int)((blockIdx.x * (long)blockDim.x + threadIdx.x) >> 6);
    int l = threadIdx.x & 63;
    if (wid >= n) return;
    int beg = off[wid], end = off[wid + 1];
    float a[8] = {};
    for (int e = beg; e < end; e++) {
        int s = csr[e];
        ushortx8 v = *(const ushortx8*)(Abuf_r + (long)s * 1024 + 512 + l * 8);
#pragma unroll
        for (int i = 0; i < 8; i++) a[i] += b2f(v[i]);
    }
    int d = end - beg;
    float inv = 1.0f / (float)(d > 0 ? d : 1);
    ushortx8 o8;
#pragma unroll
    for (int i = 0; i < 8; i++) o8[i] = f2b(a[i] * inv);
    *(ushortx8*)(Abuf_w + (long)wid * 1024 + l * 8) = o8;
}

// ---------------- Wcat[o][k] = k<512 ? W_l[o][k] : W_r[o][k-512], bf16 ----------------

__global__ void convw_kernel(const float* __restrict__ Wl, const float* __restrict__ Wr,
                             unsigned short* __restrict__ Wcat) {
    int t = blockIdx.x * blockDim.x + threadIdx.x;   // 512 * 128
    int o = t >> 7;
    int c8 = (t & 127) * 8;
    const float* p = (c8 < 512) ? (Wl + o * 512 + c8) : (Wr + o * 512 + (c8 - 512));
    float4 v0 = ((const float4*)p)[0], v1 = ((const float4*)p)[1];
    ushortx8 o8;
    o8[0] = f2b(v0.x); o8[1] = f2b(v0.y); o8[2] = f2b(v0.z); o8[3] = f2b(v0.w);
    o8[4] = f2b(v1.x); o8[5] = f2b(v1.y); o8[6] = f2b(v1.z); o8[7] = f2b(v1.w);
    *(ushortx8*)(Wcat + (long)o * 1024 + c8) = o8;
}

// ---------------- GEMM: out = A(Mx1024,bf16) . Wcat(512x1024,bf16)^T + bias ----------------
// m97 structure: 128x128 tile, BK=32, 4 waves 2x2 each 64x64 (4x4 MFMA 16x16x32)

__global__ __launch_bounds__(256, 2)
void gemm_kernel(const unsigned short* __restrict__ A, const unsigned short* __restrict__ B,
                 const float* __restrict__ bl, const int* __restrict__ deg,
                 float* __restrict__ out, int Mreal) {
    __shared__ unsigned short As[128 * 32];   // 8 KB, unpadded: global_load_lds layout
    __shared__ unsigned short Bs[128 * 32];
    int tid = threadIdx.x;
    int w = tid >> 6, l = tid & 63;
    long i0 = (long)blockIdx.y * 128;
    int n0 = blockIdx.x * 128;
    int wm = (w >> 1) * 64, wn = (w & 1) * 64;
    int r = l & 15, q = l >> 4;
    int srow = l >> 2;          // row within 16-row segment
    int sch = (l & 3) * 8;      // k-chunk (8 bf16 = 16B)

    floatx4 acc[4][4] = {};

    for (int k0 = 0; k0 < 1024; k0 += 32) {
#pragma unroll
        for (int j = 0; j < 2; j++) {
            int s = w * 2 + j;
            int row = s * 16 + srow;
            const unsigned short* ga = A + (i0 + row) * 1024 + k0 + sch;
            const unsigned short* gb = B + (long)(n0 + row) * 1024 + k0 + sch;
            __builtin_amdgcn_global_load_lds(
                (__attribute__((address_space(1))) void*)(uintptr_t)ga,
                (__attribute__((address_space(3))) void*)(uintptr_t)(As + s * 512), 16, 0, 0);
            __builtin_amdgcn_global_load_lds(
                (__attribute__((address_space(1))) void*)(uintptr_t)gb,
                (__attribute__((address_space(3))) void*)(uintptr_t)(Bs + s * 512), 16, 0, 0);
        }
        __syncthreads();
        bf16x8 af[4], bfr[4];
#pragma unroll
        for (int a = 0; a < 4; a++)
            af[a] = *(const bf16x8*)(As + (wm + a * 16 + r) * 32 + q * 8);
#pragma unroll
        for (int b = 0; b < 4; b++)
            bfr[b] = *(const bf16x8*)(Bs + (wn + b * 16 + r) * 32 + q * 8);
#pragma unroll
        for (int a = 0; a < 4; a++)
#pragma unroll
            for (int b = 0; b < 4; b++)
                acc[a][b] = __builtin_amdgcn_mfma_f32_16x16x32_bf16(af[a], bfr[b], acc[a][b], 0, 0, 0);
        __syncthreads();
    }

#pragma unroll
    for (int a = 0; a < 4; a++) {
        long rb = i0 + wm + a * 16 + q * 4;
#pragma unroll
        for (int rr = 0; rr < 4; rr++) {
            long row = rb + rr;
            if (row < Mreal) {
                bool hasdeg = deg[row] > 0;
#pragma unroll
                for (int b = 0; b < 4; b++) {
                    int col = n0 + wn + b * 16 + r;
                    float v = acc[a][b][rr];
                    if (hasdeg) v += bl[col];
                    out[row * 512 + col] = v;
                }
            }
        }
    }
}

// ---------------- launch ----------------

extern "C" void kernel_launch(void* const* d_in, const int* in_sizes, int n_in,
                              void* d_out, int out_size, void* d_ws, size_t ws_size,
                              hipStream_t stream) {
    const float* x  = (const float*)d_in[0];
    const int* eidx = (const int*)d_in[1];
    const float* Wl = (const float*)d_in[2];
    const float* bl = (const float*)d_in[3];
    const float* Wr = (const float*)d_in[4];
    float* out = (float*)d_out;

    int N  = in_sizes[0] / 512;
    int nE = in_sizes[1] / 2;
    const int* src = eidx;
    const int* dst = eidx + nE;
    int Mpad = (N + 127) & ~127;
    int nb = (N + 1023) / 1024;

    char* w = (char*)d_ws;
    size_t o = 0;
    auto alloc = [&](size_t bytes) { void* p = w + o; o = (o + bytes + 255) & ~255UL; return p; };
    int* deg    = (int*)alloc((size_t)N * 4);
    int* cursor = (int*)alloc((size_t)N * 4);
    int* off    = (int*)alloc((size_t)(N + 1) * 4);
    int* bsum   = (int*)alloc((size_t)nb * 4);
    int* csr    = (int*)alloc((size_t)nE * 4);
    unsigned short* Wcat = (unsigned short*)alloc((size_t)512 * 1024 * 2);
    unsigned short* Abuf = (unsigned short*)alloc((size_t)Mpad * 1024 * 2);
    if (o > ws_size) return;   // workspace too small -> validation will flag

    hipMemsetAsync(deg, 0, (size_t)N * 4, stream);
    hipMemsetAsync(cursor, 0, (size_t)N * 4, stream);

    deg_count_kernel<<<(nE + 255) / 256, 256, 0, stream>>>(dst, deg, nE);
    scan1_kernel<<<nb, 256, 0, stream>>>(deg, bsum, N);
    scan2_kernel<<<1, 64, 0, stream>>>(bsum, off, nb, N);
    scan3_kernel<<<nb, 256, 0, stream>>>(deg, bsum, off, N);
    fill_kernel<<<(nE + 255) / 256, 256, 0, stream>>>(src, dst, off, cursor, csr, nE);
    convx_kernel<<<(int)(((long)Mpad * 128 + 255) / 256), 256, 0, stream>>>(x, Abuf, N, Mpad);
    convw_kernel<<<(512 * 128) / 256, 256, 0, stream>>>(Wl, Wr, Wcat);
    agg_kernel<<<(N * 64 + 255) / 256, 256, 0, stream>>>(Abuf, off, csr, Abuf, N);

    dim3 g(512 / 128, Mpad / 128);   // col-block fastest: A-row reuse in L2/L3
    gemm_kernel<<<g, 256, 0, stream>>>(Abuf, Wcat, bl, deg, out, N);
}

// Round 3
// 438.894 us; speedup vs baseline: 1.4905x; 1.1048x over previous
//
#include <hip/hip_runtime.h>

typedef __bf16 bf16x8 __attribute__((ext_vector_type(8)));
typedef float floatx4 __attribute__((ext_vector_type(4)));
typedef float floatx2 __attribute__((ext_vector_type(2)));
typedef unsigned short ushortx8 __attribute__((ext_vector_type(8)));

__device__ __forceinline__ unsigned short f2b(float f) {
    union { float f; unsigned u; } v; v.f = f;
    unsigned r = v.u + 0x7fffu + ((v.u >> 16) & 1u);   // RNE
    return (unsigned short)(r >> 16);
}

// ---------------- CSR build ----------------

__global__ void deg_count_kernel(const int* __restrict__ dst, int* __restrict__ deg, int nE) {
    int e = blockIdx.x * blockDim.x + threadIdx.x;
    if (e < nE) atomicAdd(&deg[dst[e]], 1);
}

// hierarchical scan: 1024 elems per block
__global__ void scan1_kernel(const int* __restrict__ deg, int* __restrict__ bsum, int n) {
    __shared__ int s[256];
    int b = blockIdx.x, t = threadIdx.x;
    int base = b * 1024 + t * 4;
    int v = 0;
#pragma unroll
    for (int i = 0; i < 4; i++) { int idx = base + i; if (idx < n) v += deg[idx]; }
    s[t] = v; __syncthreads();
    for (int o = 128; o > 0; o >>= 1) { if (t < o) s[t] += s[t + o]; __syncthreads(); }
    if (t == 0) bsum[b] = s[0];
}

__global__ void scan2_kernel(int* __restrict__ bsum, int* __restrict__ off, int nb, int n) {
    if (threadIdx.x == 0) {
        int acc = 0;
        for (int i = 0; i < nb; i++) { int x = bsum[i]; bsum[i] = acc; acc += x; }
        off[n] = acc;
    }
}

__global__ void scan3_kernel(const int* __restrict__ deg, const int* __restrict__ bsum,
                             int* __restrict__ off, int n) {
    __shared__ int s[256];
    int b = blockIdx.x, t = threadIdx.x;
    int idx = b * 1024 + t * 4;
    int a0 = (idx     < n) ? deg[idx]     : 0;
    int a1 = (idx + 1 < n) ? deg[idx + 1] : 0;
    int a2 = (idx + 2 < n) ? deg[idx + 2] : 0;
    int a3 = (idx + 3 < n) ? deg[idx + 3] : 0;
    int tsum = a0 + a1 + a2 + a3;
    s[t] = tsum; __syncthreads();
    for (int o = 1; o < 256; o <<= 1) {
        int u = (t >= o) ? s[t - o] : 0;
        __syncthreads();
        s[t] += u;
        __syncthreads();
    }
    int excl = s[t] - tsum + bsum[b];
    if (idx     < n) off[idx]     = excl;
    if (idx + 1 < n) off[idx + 1] = excl + a0;
    if (idx + 2 < n) off[idx + 2] = excl + a0 + a1;
    if (idx + 3 < n) off[idx + 3] = excl + a0 + a1 + a2;
}

__global__ void fill_kernel(const int* __restrict__ src, const int* __restrict__ dst,
                            const int* __restrict__ off, int* __restrict__ cursor,
                            int* __restrict__ csr, int nE) {
    int e = blockIdx.x * blockDim.x + threadIdx.x;
    if (e < nE) {
        int d = dst[e];
        int pos = atomicAdd(&cursor[d], 1);
        csr[off[d] + pos] = src[e];
    }
}

// ---------------- x -> bf16 A[:, 512:1024] AND fp8 X8; zero pad rows ----------------
// one thread per 8-element chunk of a row (64 threads/row over Mpad rows)

__global__ void convx_kernel(const float* __restrict__ x, unsigned short* __restrict__ Abuf,
                             unsigned char* __restrict__ X8, int Mreal, int Mpad) {
    long t = (long)blockIdx.x * blockDim.x + threadIdx.x;
    long row = t >> 6;
    int c8 = (int)(t & 63) * 8;
    if (row >= Mpad) return;
    if (row < Mreal) {
        const float4* p4 = (const float4*)(x + row * 512 + c8);
        float4 v0 = p4[0], v1 = p4[1];
        ushortx8 o8;
        o8[0] = f2b(v0.x); o8[1] = f2b(v0.y); o8[2] = f2b(v0.z); o8[3] = f2b(v0.w);
        o8[4] = f2b(v1.x); o8[5] = f2b(v1.y); o8[6] = f2b(v1.z); o8[7] = f2b(v1.w);
        *(ushortx8*)(Abuf + row * 1024 + 512 + c8) = o8;
        unsigned int pa = __builtin_amdgcn_cvt_pk_fp8_f32(v0.x, v0.y, 0, false);
        pa = __builtin_amdgcn_cvt_pk_fp8_f32(v0.z, v0.w, pa, true);
        unsigned int pb = __builtin_amdgcn_cvt_pk_fp8_f32(v1.x, v1.y, 0, false);
        pb = __builtin_amdgcn_cvt_pk_fp8_f32(v1.z, v1.w, pb, true);
        *(uint2*)(X8 + row * 512 + c8) = make_uint2(pa, pb);
    } else {
        ushortx8 z = {0, 0, 0, 0, 0, 0, 0, 0};
        *(ushortx8*)(Abuf + row * 1024 + c8) = z;         // left half (agg never writes pad rows)
        *(ushortx8*)(Abuf + row * 1024 + 512 + c8) = z;   // right half
    }
}

// ---------------- aggregation: one wave per node, gathers fp8 x, m -> bf16 A[:, 0:512] ----

__global__ void agg_kernel(const unsigned char* __restrict__ X8,
                           const int* __restrict__ off, const int* __restrict__ csr,
                           unsigned short* __restrict__ Abuf_w, int n) {
    int wid = (int)((blockIdx.x * (long)blockDim.x + threadIdx.x) >> 6);
    int l = threadIdx.x & 63;
    if (wid >= n) return;
    int beg = off[wid], end = off[wid + 1];
    float a[8] = {};
    int e = beg;
    while (e < end) {
        int cnt = end - e; if (cnt > 64) cnt = 64;
        int myi = csr[e + (l < cnt ? l : cnt - 1)];   // batch of up to 64 indices, one per lane
        for (int j = 0; j < cnt; j++) {
            int s = __builtin_amdgcn_readlane(myi, j);
            uint2 p = *(const uint2*)(X8 + (long)s * 512 + l * 8);
            floatx2 f0 = __builtin_amdgcn_cvt_pk_f32_fp8(p.x, false);
            floatx2 f1 = __builtin_amdgcn_cvt_pk_f32_fp8(p.x, true);
            floatx2 f2 = __builtin_amdgcn_cvt_pk_f32_fp8(p.y, false);
            floatx2 f3 = __builtin_amdgcn_cvt_pk_f32_fp8(p.y, true);
            a[0] += f0[0]; a[1] += f0[1]; a[2] += f1[0]; a[3] += f1[1];
            a[4] += f2[0]; a[5] += f2[1]; a[6] += f3[0]; a[7] += f3[1];
        }
        e += cnt;
    }
    int d = end - beg;
    float inv = 1.0f / (float)(d > 0 ? d : 1);
    ushortx8 o8;
#pragma unroll
    for (int i = 0; i < 8; i++) o8[i] = f2b(a[i] * inv);
    *(ushortx8*)(Abuf_w + (long)wid * 1024 + l * 8) = o8;
}

// ---------------- Wcat[o][k] = k<512 ? W_l[o][k] : W_r[o][k-512], bf16 ----------------

__global__ void convw_kernel(const float* __restrict__ Wl, const float* __restrict__ Wr,
                             unsigned short* __restrict__ Wcat) {
    int t = blockIdx.x * blockDim.x + threadIdx.x;   // 512 * 128
    int o = t >> 7;
    int c8 = (t & 127) * 8;
    const float* p = (c8 < 512) ? (Wl + o * 512 + c8) : (Wr + o * 512 + (c8 - 512));
    float4 v0 = ((const float4*)p)[0], v1 = ((const float4*)p)[1];
    ushortx8 o8;
    o8[0] = f2b(v0.x); o8[1] = f2b(v0.y); o8[2] = f2b(v0.z); o8[3] = f2b(v0.w);
    o8[4] = f2b(v1.x); o8[5] = f2b(v1.y); o8[6] = f2b(v1.z); o8[7] = f2b(v1.w);
    *(ushortx8*)(Wcat + (long)o * 1024 + c8) = o8;
}

// ---------------- GEMM: out = A(Mx1024,bf16) . Wcat(512x1024,bf16)^T + bias ----------------
// m97 structure: 128x128 tile, BK=32, 4 waves 2x2 each 64x64 (4x4 MFMA 16x16x32)

__global__ __launch_bounds__(256, 2)
void gemm_kernel(const unsigned short* __restrict__ A, const unsigned short* __restrict__ B,
                 const float* __restrict__ bl, const int* __restrict__ deg,
                 float* __restrict__ out, int Mreal) {
    __shared__ unsigned short As[128 * 32];   // 8 KB, unpadded: global_load_lds layout
    __shared__ unsigned short Bs[128 * 32];
    int tid = threadIdx.x;
    int w = tid >> 6, l = tid & 63;
    long i0 = (long)blockIdx.y * 128;
    int n0 = blockIdx.x * 128;
    int wm = (w >> 1) * 64, wn = (w & 1) * 64;
    int r = l & 15, q = l >> 4;
    int srow = l >> 2;          // row within 16-row segment
    int sch = (l & 3) * 8;      // k-chunk (8 bf16 = 16B)

    floatx4 acc[4][4] = {};

    for (int k0 = 0; k0 < 1024; k0 += 32) {
#pragma unroll
        for (int j = 0; j < 2; j++) {
            int s = w * 2 + j;
            int row = s * 16 + srow;
            const unsigned short* ga = A + (i0 + row) * 1024 + k0 + sch;
            const unsigned short* gb = B + (long)(n0 + row) * 1024 + k0 + sch;
            __builtin_amdgcn_global_load_lds(
                (__attribute__((address_space(1))) void*)(uintptr_t)ga,
                (__attribute__((address_space(3))) void*)(uintptr_t)(As + s * 512), 16, 0, 0);
            __builtin_amdgcn_global_load_lds(
                (__attribute__((address_space(1))) void*)(uintptr_t)gb,
                (__attribute__((address_space(3))) void*)(uintptr_t)(Bs + s * 512), 16, 0, 0);
        }
        __syncthreads();
        bf16x8 af[4], bfr[4];
#pragma unroll
        for (int a = 0; a < 4; a++)
            af[a] = *(const bf16x8*)(As + (wm + a * 16 + r) * 32 + q * 8);
#pragma unroll
        for (int b = 0; b < 4; b++)
            bfr[b] = *(const bf16x8*)(Bs + (wn + b * 16 + r) * 32 + q * 8);
#pragma unroll
        for (int a = 0; a < 4; a++)
#pragma unroll
            for (int b = 0; b < 4; b++)
                acc[a][b] = __builtin_amdgcn_mfma_f32_16x16x32_bf16(af[a], bfr[b], acc[a][b], 0, 0, 0);
        __syncthreads();
    }

#pragma unroll
    for (int a = 0; a < 4; a++) {
        long rb = i0 + wm + a * 16 + q * 4;
#pragma unroll
        for (int rr = 0; rr < 4; rr++) {
            long row = rb + rr;
            if (row < Mreal) {
                bool hasdeg = deg[row] > 0;
#pragma unroll
                for (int b = 0; b < 4; b++) {
                    int col = n0 + wn + b * 16 + r;
                    float v = acc[a][b][rr];
                    if (hasdeg) v += bl[col];
                    out[row * 512 + col] = v;
                }
            }
        }
    }
}

// ---------------- launch ----------------

extern "C" void kernel_launch(void* const* d_in, const int* in_sizes, int n_in,
                              void* d_out, int out_size, void* d_ws, size_t ws_size,
                              hipStream_t stream) {
    const float* x  = (const float*)d_in[0];
    const int* eidx = (const int*)d_in[1];
    const float* Wl = (const float*)d_in[2];
    const float* bl = (const float*)d_in[3];
    const float* Wr = (const float*)d_in[4];
    float* out = (float*)d_out;

    int N  = in_sizes[0] / 512;
    int nE = in_sizes[1] / 2;
    const int* src = eidx;
    const int* dst = eidx + nE;
    int Mpad = (N + 127) & ~127;
    int nb = (N + 1023) / 1024;

    char* w = (char*)d_ws;
    size_t o = 0;
    auto alloc = [&](size_t bytes) { void* p = w + o; o = (o + bytes + 255) & ~255UL; return p; };
    int* deg    = (int*)alloc((size_t)N * 4);
    int* cursor = (int*)alloc((size_t)N * 4);
    int* off    = (int*)alloc((size_t)(N + 1) * 4);
    int* bsum   = (int*)alloc((size_t)nb * 4);
    int* csr    = (int*)alloc((size_t)nE * 4);
    unsigned short* Wcat = (unsigned short*)alloc((size_t)512 * 1024 * 2);
    unsigned short* Abuf = (unsigned short*)alloc((size_t)Mpad * 1024 * 2);
    unsigned char*  X8   = (unsigned char*)alloc((size_t)Mpad * 512);
    if (o > ws_size) return;   // workspace too small -> validation will flag

    hipMemsetAsync(deg, 0, (size_t)N * 4, stream);
    hipMemsetAsync(cursor, 0, (size_t)N * 4, stream);

    deg_count_kernel<<<(nE + 255) / 256, 256, 0, stream>>>(dst, deg, nE);
    scan1_kernel<<<nb, 256, 0, stream>>>(deg, bsum, N);
    scan2_kernel<<<1, 64, 0, stream>>>(bsum, off, nb, N);
    scan3_kernel<<<nb, 256, 0, stream>>>(deg, bsum, off, N);
    fill_kernel<<<(nE + 255) / 256, 256, 0, stream>>>(src, dst, off, cursor, csr, nE);
    convx_kernel<<<(int)(((long)Mpad * 64 + 255) / 256), 256, 0, stream>>>(x, Abuf, X8, N, Mpad);
    convw_kernel<<<(512 * 128) / 256, 256, 0, stream>>>(Wl, Wr, Wcat);
    agg_kernel<<<(N * 64 + 255) / 256, 256, 0, stream>>>(X8, off, csr, Abuf, N);

    dim3 g(512 / 128, Mpad / 128);   // col-block fastest: A-row reuse in L2/L3
    gemm_kernel<<<g, 256, 0, stream>>>(Abuf, Wcat, bl, deg, out, N);
}

// Round 4
// 412.202 us; speedup vs baseline: 1.5870x; 1.0648x over previous
//
#include <hip/hip_runtime.h>

typedef __bf16 bf16x8 __attribute__((ext_vector_type(8)));
typedef float floatx4 __attribute__((ext_vector_type(4)));
typedef float floatx2 __attribute__((ext_vector_type(2)));
typedef unsigned short ushortx8 __attribute__((ext_vector_type(8)));

__device__ __forceinline__ unsigned short f2b(float f) {
    union { float f; unsigned u; } v; v.f = f;
    unsigned r = v.u + 0x7fffu + ((v.u >> 16) & 1u);   // RNE
    return (unsigned short)(r >> 16);
}

// ---------------- CSR build ----------------

__global__ void deg_count_kernel(const int* __restrict__ dst, int* __restrict__ deg, int nE) {
    int e = blockIdx.x * blockDim.x + threadIdx.x;
    if (e < nE) atomicAdd(&deg[dst[e]], 1);
}

// hierarchical scan: 1024 elems per block
__global__ void scan1_kernel(const int* __restrict__ deg, int* __restrict__ bsum, int n) {
    __shared__ int s[256];
    int b = blockIdx.x, t = threadIdx.x;
    int base = b * 1024 + t * 4;
    int v = 0;
#pragma unroll
    for (int i = 0; i < 4; i++) { int idx = base + i; if (idx < n) v += deg[idx]; }
    s[t] = v; __syncthreads();
    for (int o = 128; o > 0; o >>= 1) { if (t < o) s[t] += s[t + o]; __syncthreads(); }
    if (t == 0) bsum[b] = s[0];
}

// scan3: per-block local scan; block base = sum of bsum[0..b) via in-block wave reduce (nb<=64)
__global__ void scan3_kernel(const int* __restrict__ deg, const int* __restrict__ bsum,
                             int* __restrict__ off, int n, int nb, int nE) {
    __shared__ int s[256];
    __shared__ int base_s;
    int b = blockIdx.x, t = threadIdx.x;
    if (t < 64) {
        int v = (t < nb && t < b) ? bsum[t] : 0;
        for (int o = 32; o > 0; o >>= 1) v += __shfl_down(v, o, 64);
        if (t == 0) base_s = v;
    }
    int idx = b * 1024 + t * 4;
    int a0 = (idx     < n) ? deg[idx]     : 0;
    int a1 = (idx + 1 < n) ? deg[idx + 1] : 0;
    int a2 = (idx + 2 < n) ? deg[idx + 2] : 0;
    int a3 = (idx + 3 < n) ? deg[idx + 3] : 0;
    int tsum = a0 + a1 + a2 + a3;
    s[t] = tsum; __syncthreads();
    for (int o = 1; o < 256; o <<= 1) {
        int u = (t >= o) ? s[t - o] : 0;
        __syncthreads();
        s[t] += u;
        __syncthreads();
    }
    int excl = s[t] - tsum + base_s;
    if (idx     < n) off[idx]     = excl;
    if (idx + 1 < n) off[idx + 1] = excl + a0;
    if (idx + 2 < n) off[idx + 2] = excl + a0 + a1;
    if (idx + 3 < n) off[idx + 3] = excl + a0 + a1 + a2;
    if (b == 0 && t == 0) off[n] = nE;
}

__global__ void fill_kernel(const int* __restrict__ src, const int* __restrict__ dst,
                            const int* __restrict__ off, int* __restrict__ cursor,
                            int* __restrict__ csr, int nE) {
    int e = blockIdx.x * blockDim.x + threadIdx.x;
    if (e < nE) {
        int d = dst[e];
        int pos = atomicAdd(&cursor[d], 1);
        csr[off[d] + pos] = src[e];
    }
}

// ---------------- fused conversions ----------------
// threads [0, Mpad*64): x -> bf16 A[:,512:1024] + fp8 X8 (pad rows zeroed)
// threads [Mpad*64, +65536): Wcat[o][k] = k<512 ? Wl[o][k] : Wr[o][k-512] (bf16)

__global__ void conv_kernel(const float* __restrict__ x, unsigned short* __restrict__ Abuf,
                            unsigned char* __restrict__ X8,
                            const float* __restrict__ Wl, const float* __restrict__ Wr,
                            unsigned short* __restrict__ Wcat,
                            int Mreal, long nx) {
    long t = (long)blockIdx.x * blockDim.x + threadIdx.x;
    if (t < nx) {
        long row = t >> 6;
        int c8 = (int)(t & 63) * 8;
        if (row < Mreal) {
            const float4* p4 = (const float4*)(x + row * 512 + c8);
            float4 v0 = p4[0], v1 = p4[1];
            ushortx8 o8;
            o8[0] = f2b(v0.x); o8[1] = f2b(v0.y); o8[2] = f2b(v0.z); o8[3] = f2b(v0.w);
            o8[4] = f2b(v1.x); o8[5] = f2b(v1.y); o8[6] = f2b(v1.z); o8[7] = f2b(v1.w);
            *(ushortx8*)(Abuf + row * 1024 + 512 + c8) = o8;
            unsigned int pa = __builtin_amdgcn_cvt_pk_fp8_f32(v0.x, v0.y, 0, false);
            pa = __builtin_amdgcn_cvt_pk_fp8_f32(v0.z, v0.w, pa, true);
            unsigned int pb = __builtin_amdgcn_cvt_pk_fp8_f32(v1.x, v1.y, 0, false);
            pb = __builtin_amdgcn_cvt_pk_fp8_f32(v1.z, v1.w, pb, true);
            *(uint2*)(X8 + row * 512 + c8) = make_uint2(pa, pb);
        } else {
            ushortx8 z = {0, 0, 0, 0, 0, 0, 0, 0};
            *(ushortx8*)(Abuf + row * 1024 + c8) = z;
            *(ushortx8*)(Abuf + row * 1024 + 512 + c8) = z;
        }
    } else {
        long u = t - nx;
        if (u >= 65536) return;
        int o = (int)(u >> 7);
        int c8 = (int)(u & 127) * 8;
        const float* p = (c8 < 512) ? (Wl + o * 512 + c8) : (Wr + o * 512 + (c8 - 512));
        float4 v0 = ((const float4*)p)[0], v1 = ((const float4*)p)[1];
        ushortx8 o8;
        o8[0] = f2b(v0.x); o8[1] = f2b(v0.y); o8[2] = f2b(v0.z); o8[3] = f2b(v0.w);
        o8[4] = f2b(v1.x); o8[5] = f2b(v1.y); o8[6] = f2b(v1.z); o8[7] = f2b(v1.w);
        *(ushortx8*)(Wcat + (long)o * 1024 + c8) = o8;
    }
}

// ---------------- aggregation: one wave per node, gathers fp8 x, m -> bf16 A[:, 0:512] ----

__global__ void agg_kernel(const unsigned char* __restrict__ X8,
                           const int* __restrict__ off, const int* __restrict__ csr,
                           unsigned short* __restrict__ Abuf_w, int n) {
    int wid = (int)((blockIdx.x * (long)blockDim.x + threadIdx.x) >> 6);
    int l = threadIdx.x & 63;
    if (wid >= n) return;
    int beg = off[wid], end = off[wid + 1];
    float a[8] = {};
    int e = beg;
    while (e < end) {
        int cnt = end - e; if (cnt > 64) cnt = 64;
        int myi = csr[e + (l < cnt ? l : cnt - 1)];   // batch of up to 64 indices, one per lane
        int s0 = __builtin_amdgcn_readlane(myi, 0);
        uint2 p = *(const uint2*)(X8 + (long)s0 * 512 + l * 8);
        for (int j = 1; j < cnt; j++) {
            int s = __builtin_amdgcn_readlane(myi, j);
            uint2 pn = *(const uint2*)(X8 + (long)s * 512 + l * 8);   // prefetch next
            floatx2 f0 = __builtin_amdgcn_cvt_pk_f32_fp8(p.x, false);
            floatx2 f1 = __builtin_amdgcn_cvt_pk_f32_fp8(p.x, true);
            floatx2 f2 = __builtin_amdgcn_cvt_pk_f32_fp8(p.y, false);
            floatx2 f3 = __builtin_amdgcn_cvt_pk_f32_fp8(p.y, true);
            a[0] += f0[0]; a[1] += f0[1]; a[2] += f1[0]; a[3] += f1[1];
            a[4] += f2[0]; a[5] += f2[1]; a[6] += f3[0]; a[7] += f3[1];
            p = pn;
        }
        {
            floatx2 f0 = __builtin_amdgcn_cvt_pk_f32_fp8(p.x, false);
            floatx2 f1 = __builtin_amdgcn_cvt_pk_f32_fp8(p.x, true);
            floatx2 f2 = __builtin_amdgcn_cvt_pk_f32_fp8(p.y, false);
            floatx2 f3 = __builtin_amdgcn_cvt_pk_f32_fp8(p.y, true);
            a[0] += f0[0]; a[1] += f0[1]; a[2] += f1[0]; a[3] += f1[1];
            a[4] += f2[0]; a[5] += f2[1]; a[6] += f3[0]; a[7] += f3[1];
        }
        e += cnt;
    }
    int d = end - beg;
    float inv = 1.0f / (float)(d > 0 ? d : 1);
    ushortx8 o8;
#pragma unroll
    for (int i = 0; i < 8; i++) o8[i] = f2b(a[i] * inv);
    *(ushortx8*)(Abuf_w + (long)wid * 1024 + l * 8) = o8;
}

// ---------------- GEMM: out = A(Mx1024,bf16) . Wcat(512x1024,bf16)^T + bias ----------------
// m97 structure: 128x128 tile, BK=32, 4 waves 2x2 each 64x64 (4x4 MFMA 16x16x32)
// XCD swizzle: the 4 col-blocks of one row-stripe land on the SAME XCD (L2 A-reuse)

__global__ __launch_bounds__(256, 3)
void gemm_kernel(const unsigned short* __restrict__ A, const unsigned short* __restrict__ B,
                 const float* __restrict__ bl, const int* __restrict__ deg,
                 float* __restrict__ out, int Mreal, int nby) {
    int L = blockIdx.x;
    int by = (L >> 5) * 8 + (L & 7);   // row-stripe
    int bx = (L >> 3) & 3;             // col-block: shares XCD (L%8) with its 3 siblings
    if (by >= nby) return;

    __shared__ unsigned short As[128 * 32];   // 8 KB, unpadded: global_load_lds layout
    __shared__ unsigned short Bs[128 * 32];
    int tid = threadIdx.x;
    int w = tid >> 6, l = tid & 63;
    long i0 = (long)by * 128;
    int n0 = bx * 128;
    int wm = (w >> 1) * 64, wn = (w & 1) * 64;
    int r = l & 15, q = l >> 4;
    int srow = l >> 2;          // row within 16-row segment
    int sch = (l & 3) * 8;      // k-chunk (8 bf16 = 16B)

    floatx4 acc[4][4] = {};

    for (int k0 = 0; k0 < 1024; k0 += 32) {
#pragma unroll
        for (int j = 0; j < 2; j++) {
            int s = w * 2 + j;
            int row = s * 16 + srow;
            const unsigned short* ga = A + (i0 + row) * 1024 + k0 + sch;
            const unsigned short* gb = B + (long)(n0 + row) * 1024 + k0 + sch;
            __builtin_amdgcn_global_load_lds(
                (__attribute__((address_space(1))) void*)(uintptr_t)ga,
                (__attribute__((address_space(3))) void*)(uintptr_t)(As + s * 512), 16, 0, 0);
            __builtin_amdgcn_global_load_lds(
                (__attribute__((address_space(1))) void*)(uintptr_t)gb,
                (__attribute__((address_space(3))) void*)(uintptr_t)(Bs + s * 512), 16, 0, 0);
        }
        __syncthreads();
        bf16x8 af[4], bfr[4];
#pragma unroll
        for (int a = 0; a < 4; a++)
            af[a] = *(const bf16x8*)(As + (wm + a * 16 + r) * 32 + q * 8);
#pragma unroll
        for (int b = 0; b < 4; b++)
            bfr[b] = *(const bf16x8*)(Bs + (wn + b * 16 + r) * 32 + q * 8);
#pragma unroll
        for (int a = 0; a < 4; a++)
#pragma unroll
            for (int b = 0; b < 4; b++)
                acc[a][b] = __builtin_amdgcn_mfma_f32_16x16x32_bf16(af[a], bfr[b], acc[a][b], 0, 0, 0);
        __syncthreads();
    }

#pragma unroll
    for (int a = 0; a < 4; a++) {
        long rb = i0 + wm + a * 16 + q * 4;
#pragma unroll
        for (int rr = 0; rr < 4; rr++) {
            long row = rb + rr;
            if (row < Mreal) {
                bool hasdeg = deg[row] > 0;
#pragma unroll
                for (int b = 0; b < 4; b++) {
                    int col = n0 + wn + b * 16 + r;
                    float v = acc[a][b][rr];
                    if (hasdeg) v += bl[col];
                    out[row * 512 + col] = v;
                }
            }
        }
    }
}

// ---------------- launch ----------------

extern "C" void kernel_launch(void* const* d_in, const int* in_sizes, int n_in,
                              void* d_out, int out_size, void* d_ws, size_t ws_size,
                              hipStream_t stream) {
    const float* x  = (const float*)d_in[0];
    const int* eidx = (const int*)d_in[1];
    const float* Wl = (const float*)d_in[2];
    const float* bl = (const float*)d_in[3];
    const float* Wr = (const float*)d_in[4];
    float* out = (float*)d_out;

    int N  = in_sizes[0] / 512;
    int nE = in_sizes[1] / 2;
    const int* src = eidx;
    const int* dst = eidx + nE;
    int Mpad = (N + 127) & ~127;
    int nb = (N + 1023) / 1024;
    int nby = Mpad / 128;

    char* w = (char*)d_ws;
    size_t o = 0;
    auto alloc = [&](size_t bytes) { void* p = w + o; o = (o + bytes + 255) & ~255UL; return p; };
    int* deg    = (int*)alloc((size_t)N * 4);
    int* cursor = (int*)alloc((size_t)N * 4);
    int* off    = (int*)alloc((size_t)(N + 1) * 4);
    int* bsum   = (int*)alloc((size_t)nb * 4);
    int* csr    = (int*)alloc((size_t)nE * 4);
    unsigned short* Wcat = (unsigned short*)alloc((size_t)512 * 1024 * 2);
    unsigned short* Abuf = (unsigned short*)alloc((size_t)Mpad * 1024 * 2);
    unsigned char*  X8   = (unsigned char*)alloc((size_t)Mpad * 512);
    if (o > ws_size) return;   // workspace too small -> validation will flag

    hipMemsetAsync(deg, 0, (size_t)N * 4, stream);
    hipMemsetAsync(cursor, 0, (size_t)N * 4, stream);

    deg_count_kernel<<<(nE + 255) / 256, 256, 0, stream>>>(dst, deg, nE);
    scan1_kernel<<<nb, 256, 0, stream>>>(deg, bsum, N);
    scan3_kernel<<<nb, 256, 0, stream>>>(deg, bsum, off, N, nb, nE);
    fill_kernel<<<(nE + 255) / 256, 256, 0, stream>>>(src, dst, off, cursor, csr, nE);
    long nx = (long)Mpad * 64;
    conv_kernel<<<(int)((nx + 65536 + 255) / 256), 256, 0, stream>>>(x, Abuf, X8, Wl, Wr, Wcat, N, nx);
    agg_kernel<<<(N * 64 + 255) / 256, 256, 0, stream>>>(X8, off, csr, Abuf, N);

    int nbyp = (nby + 7) & ~7;
    gemm_kernel<<<nbyp * 4, 256, 0, stream>>>(Abuf, Wcat, bl, deg, out, N, nby);
}